// Round 1
// baseline (172.427 us; speedup 1.0000x reference)
//
#include <hip/hip_runtime.h>

// out[p, :] = W[i1[p], :] + (i1[p] != i2[p] ? W[i2[p], :] : 0)
// P = B*S = 32768 positions, D = 512 fp32 per row -> 128 float4 per row.
// One thread per output float4; 128 consecutive threads share one position.

#define EMB_DIM 512
#define QUADS_PER_ROW (EMB_DIM / 4)   // 128

__global__ __launch_bounds__(256) void twohot_kernel(
    const int* __restrict__ idx1,
    const int* __restrict__ idx2,
    const float4* __restrict__ w4,   // [VOCAB * 128]
    float4* __restrict__ out4,       // [P * 128]
    int total_quads)
{
    int gid = blockIdx.x * blockDim.x + threadIdx.x;
    if (gid >= total_quads) return;

    int pos = gid >> 7;          // gid / 128
    int q   = gid & (QUADS_PER_ROW - 1);

    int i1 = idx1[pos];
    int i2 = idx2[pos];

    float4 v = w4[(long)i1 * QUADS_PER_ROW + q];
    if (i2 != i1) {
        float4 v2 = w4[(long)i2 * QUADS_PER_ROW + q];
        v.x += v2.x; v.y += v2.y; v.z += v2.z; v.w += v2.w;
    }
    out4[gid] = v;
}

extern "C" void kernel_launch(void* const* d_in, const int* in_sizes, int n_in,
                              void* d_out, int out_size, void* d_ws, size_t ws_size,
                              hipStream_t stream) {
    const int*   idx1 = (const int*)d_in[0];    // input_one [B,S] int32
    const int*   idx2 = (const int*)d_in[1];    // input_two [B,S] int32
    const float4* w4  = (const float4*)d_in[2]; // weight [VOCAB, 512] fp32
    float4* out4      = (float4*)d_out;         // [B,S,512] fp32

    int total_quads = out_size / 4;             // out_size = B*S*512
    int block = 256;
    int grid  = (total_quads + block - 1) / block;
    twohot_kernel<<<grid, block, 0, stream>>>(idx1, idx2, w4, out4, total_quads);
}